// Round 12
// baseline (196.741 us; speedup 1.0000x reference)
//
#include <hip/hip_runtime.h>

// Fused LSTM(H=128) + 3-layer MLP head, fp16 MFMA (16x16x32), fp32 state.
// B=8192 rows, T=30 steps. 256 blocks x 512 threads (8 waves), 32 rows/block.
// ROUND 12 (on r11's 86.4us staggered-M-tile base):
//  (1) T19 sched_group_barrier in warm regions: r11's regions contain both
//      MFMA work (m-tile X) and independent VALU/trans work (m-tile Y), but
//      the compiler clusters them -> pipes alternate (MfmaUtil 26/VALUBusy 50,
//      region time ~ sum not max). Pin 14x{13 VALU, 2 MFMA}, VALU-first so
//      gates (register-only) issue while z's ds_reads are in flight.
//      Observable: lstm_mfma dur. Null -> structural plateau.
//  (2) pack_weights kernel DELETED: each thread gathers its 28 B-fragments
//      directly from raw fp32 Wi/Wh/W1/W2 at startup ((_Float16) convert =
//      bit-identical to the old pack+load). Removes a launch from the graph.
//      Observable: e2e-minus-kernel gap (~91.5us in r11).
//      FETCH_SIZE rises to ~6-10MB (raw weight reads) - expected, NOT spill.
// Staggered warm (r11): region A_i: m0 z(i)+MLP1(i-1) [MFMA] | m1 gates(i-1)+
// MLP2(i-2)+head(i-2,rows0-15) [VALU]; region B_i swaps roles. 2 barriers/step.
// Tail s=24..29: r7's TA/TB/TC/TD (p-inject via acc += p*wi7).
// Prior lessons: 2 waves/SIMD is the reg ceiling (r4/r5 spills); fp16 single
// precision (r7); no shuffle-head (r10); no async gather split (r8).
// - Wave w owns output cols [16w,16w+16); 2 M-tiles (rows 0-15,16-31).
// - 16x16x32 layouts: A/B: row|col=lane&15, k=(lane>>4)*8+j; C/D: col=lane&15,
//   row=(lane>>4)*4+reg (m89-verified).
// - A-panels [16 rows][40 halfs] (32 data + 8 pad): 16B-aligned b128 reads.
// - fp32: accumulators, c-state, gates, o2, head, feedback p.

#define T_STEPS 30
#define WARM_N  24

typedef _Float16 h8 __attribute__((ext_vector_type(8)));     // 8 fp16 = 4 VGPRs
typedef __attribute__((ext_vector_type(4))) float float4v;   // MFMA 16x16 C/D

struct FeatPtrs { const float* f[7]; };

#if __has_builtin(__builtin_amdgcn_rcpf)
#define RCP(x) __builtin_amdgcn_rcpf(x)
#else
#define RCP(x) (1.0f/(x))
#endif

__device__ __forceinline__ float sigm(float x){ return RCP(1.0f + __expf(-x)); }
__device__ __forceinline__ float tanh_(float x){ return 1.0f - 2.0f*RCP(1.0f + __expf(2.0f*x)); }

#define MFMA16 __builtin_amdgcn_mfma_f32_16x16x32_f16

// ---------------- region building blocks ----------------
#define INIT_ACC(ACC) \
  _Pragma("unroll") for (int g_ = 0; g_ < 4; ++g_) \
    _Pragma("unroll") for (int r_ = 0; r_ < 4; ++r_) ACC[g_][r_] = bzv[g_];

#define INIT4(V, B) \
  _Pragma("unroll") for (int r_ = 0; r_ < 4; ++r_) V[r_] = (B);

// z-GEMM for one m-tile (+ optionally MLP1 fused on the same h reads)
#define ZA(ACC, M1V, XBUF, HOFF, DO1) \
  { h8 ax_ = *(const h8*)&xp[XBUF][(HOFF) + aoff]; \
    _Pragma("unroll") for (int g_ = 0; g_ < 4; ++g_) \
      ACC[g_] = MFMA16(ax_, Bz[g_][0], ACC[g_], 0, 0, 0); } \
  _Pragma("unroll") for (int ks_ = 0; ks_ < 4; ++ks_){ \
    h8 ah_ = *(const h8*)&hp[ks_ * 1280 + (HOFF) + aoff]; \
    _Pragma("unroll") for (int g_ = 0; g_ < 4; ++g_) \
      ACC[g_] = MFMA16(ah_, Bz[g_][1 + ks_], ACC[g_], 0, 0, 0); \
    if (DO1) M1V = MFMA16(ah_, B1f[ks_], M1V, 0, 0, 0); }

#define WRITE_O1(M1V, HOFF) \
  _Pragma("unroll") for (int r_ = 0; r_ < 4; ++r_) \
    o1p[wb + (HOFF) + (kq * 4 + r_) * 40] = (_Float16)fmaxf(M1V[r_], 0.0f);

#define GATES(ACC, CB, HOFF) \
  _Pragma("unroll") for (int r_ = 0; r_ < 4; ++r_){ \
    float zi_ = ACC[0][r_], zf_ = ACC[1][r_], zg_ = ACC[2][r_], zo_ = ACC[3][r_]; \
    float c2_ = sigm(zf_) * cst[(CB) + r_] + sigm(zi_) * tanh_(zg_); \
    cst[(CB) + r_] = c2_; \
    float h2_ = sigm(zo_) * tanh_(c2_); \
    hp[wb + (HOFF) + (kq * 4 + r_) * 40] = (_Float16)h2_; }

#define DO_MLP2(HOFF, ROWB) \
  { float4v m2_; INIT4(m2_, b2v) \
    _Pragma("unroll") for (int ks_ = 0; ks_ < 4; ++ks_){ \
      h8 a_ = *(const h8*)&o1p[ks_ * 1280 + (HOFF) + aoff]; \
      m2_ = MFMA16(a_, B2f[ks_], m2_, 0, 0, 0); } \
    _Pragma("unroll") for (int r_ = 0; r_ < 4; ++r_) \
      o2s[((ROWB) + kq * 4 + r_) * 132 + w * 16 + c16] = fmaxf(m2_[r_], 0.0f); }

// head for one 16-row half: 8 threads/row, 16-col strips, fp32 exact
#define HEAD_HALF(TLO, RB, STEP) \
  if (t >= (TLO) && t < (TLO) + 128){ \
    int r_ = (RB) + ((t - (TLO)) >> 3), jj_ = t & 7; \
    const float* orow_ = &o2s[r_ * 132 + jj_ * 16]; \
    const float* wrow_ = &WoutS[jj_ * 16]; \
    float s_ = 0.0f; \
    _Pragma("unroll") for (int q_ = 0; q_ < 16; ++q_) s_ += orow_[q_] * wrow_[q_]; \
    s_ += __shfl_down(s_, 4, 8); s_ += __shfl_down(s_, 2, 8); s_ += __shfl_down(s_, 1, 8); \
    if (jj_ == 0){ float pv_ = s_ + bout0; \
      out[(r0 + r_) * T_STEPS + (STEP)] = pv_; pS[r_] = pv_; } }

#define STAGE_WARM(STEP, BUF) \
  if (t < 256){ \
    float v_ = 0.0f; \
    if (fbase) v_ = fbase[STEP]; \
    else if ((STEP) < WARM_N) v_ = ibase[STEP]; \
    xp[BUF][xslot] = (_Float16)v_; }

#define STAGE_TAIL(STEP, BUF) \
  if (t < 256){ \
    float v_ = fbase ? fbase[STEP] : 0.0f; \
    xp[BUF][xslot] = (_Float16)v_; }

// T19: pin 14 x {13 VALU, 2 MFMA} per warm region (VALU-first so the
// register-only gates issue while z's ds_reads are outstanding).
#define SGB_PAIR \
  __builtin_amdgcn_sched_group_barrier(0x002, 13, 0); \
  __builtin_amdgcn_sched_group_barrier(0x008, 2, 0);
#define SGB_REGION \
  SGB_PAIR SGB_PAIR SGB_PAIR SGB_PAIR SGB_PAIR SGB_PAIR SGB_PAIR \
  SGB_PAIR SGB_PAIR SGB_PAIR SGB_PAIR SGB_PAIR SGB_PAIR SGB_PAIR

// ---------------- main kernel ----------------
__global__ __launch_bounds__(512, 2)
void lstm_mfma(FeatPtrs fp, const float* __restrict__ irr,
               const float* __restrict__ Wi, const float* __restrict__ Wh,
               const float* __restrict__ bz, const float* __restrict__ W1,
               const float* __restrict__ b1, const float* __restrict__ W2,
               const float* __restrict__ b2, const float* __restrict__ Wout,
               const float* __restrict__ bout, float* __restrict__ out)
{
  // A-panels: [m-tile][16 rows][40 halfs] (32 data + 8 pad), b128-aligned
  __shared__ __align__(16) _Float16 xp[2][1280];    // x, double-buffered steps
  __shared__ __align__(16) _Float16 hp [4 * 1280];  // h, single (halves alternate)
  __shared__ __align__(16) _Float16 o1p[4 * 1280];  // o1, single
  __shared__ __align__(16) float o2s[32 * 132];     // o2 fp32, padded rows
  __shared__ float WoutS[128];
  __shared__ float pS[32];

  const int t   = threadIdx.x;
  const int l   = t & 63;
  const int w   = t >> 6;        // wave 0..7, owns cols [16w,16w+16)
  const int c16 = l & 15;
  const int kq  = l >> 4;        // 0..3
  const int r0  = blockIdx.x * 32;
  const int colz = w * 16 + c16; // this lane's column within a 128-wide tile

  // ---- build weight fragments directly from raw fp32 (pack inlined) ----
  // frag elem (lane,j): k = kq*8 + j within the kstep; col = tile col.
  // (_Float16) conversions identical to the old pack kernel -> bit-identical.
  h8 Bz[4][5], B1f[4], B2f[4];
#pragma unroll
  for (int g = 0; g < 4; ++g){
    int col = g * 128 + colz;
    h8 bx;
#pragma unroll
    for (int j = 0; j < 8; ++j)
      bx[j] = (kq == 0) ? (_Float16)Wi[j * 512 + col] : (_Float16)0.0f;
    Bz[g][0] = bx;
#pragma unroll
    for (int ks = 0; ks < 4; ++ks){
      h8 bh;
#pragma unroll
      for (int j = 0; j < 8; ++j)
        bh[j] = (_Float16)Wh[(ks * 32 + kq * 8 + j) * 512 + col];
      Bz[g][1 + ks] = bh;
    }
  }
#pragma unroll
  for (int ks = 0; ks < 4; ++ks){
    h8 b1f, b2f;
#pragma unroll
    for (int j = 0; j < 8; ++j){
      b1f[j] = (_Float16)W1[(ks * 32 + kq * 8 + j) * 128 + colz];
      b2f[j] = (_Float16)W2[(ks * 32 + kq * 8 + j) * 128 + colz];
    }
    B1f[ks] = b1f; B2f[ks] = b2f;
  }
  float bzv[4], wi7[4];
#pragma unroll
  for (int g = 0; g < 4; ++g){
    bzv[g] = bz[g * 128 + colz];
    // Wi[7][col] through the SAME fp16 rounding the x-MFMA frag would use
    wi7[g] = (float)(_Float16)Wi[7 * 512 + g * 128 + colz];
  }
  const float b1v   = b1[colz];
  const float b2v   = b2[colz];
  const float bout0 = bout[0];
  if (t < 128) WoutS[t] = Wout[t];

  // per-thread gather bases (threads t<256 own one (row,feature) slot)
  const float* fbase = nullptr;   // feature array base (j<7)
  const float* ibase = nullptr;   // irradiance base (j==7)
  int xslot = 0;
  if (t < 256){
    int r = t >> 3, j = t & 7;
    if (j < 7) fbase = fp.f[j] + (r0 + r) * T_STEPS;
    else       ibase = irr + (r0 + r) * WARM_N;
    xslot = (r >> 4) * 640 + (r & 15) * 40 + j;
  }

  { // zero x buffers (k8..31 pads stay 0 forever) and h panels (h(-1)=0)
    int* zp = (int*)&xp[0][0];
    for (int i = t; i < 1280; i += 512) zp[i] = 0;
    zp = (int*)hp;
    for (int i = t; i < 2560; i += 512) zp[i] = 0;
  }

  float cst[8];   // [0..3]=m0 rows0-15, [4..7]=m1 rows16-31
#pragma unroll
  for (int i = 0; i < 8; ++i) cst[i] = 0.0f;

  const int aoff = c16 * 40 + kq * 8;                    // A-frag read offset
  const int wb   = (w >> 1) * 1280 + (w & 1) * 16 + c16; // h/o1 write base
  __syncthreads();

  // prologue: gather x(0) into xp[0]
  if (t < 256){
    float v0 = fbase ? fbase[0] : ibase[0];
    xp[0][xslot] = (_Float16)v0;
  }
  __syncthreads();

  float4v acc0[4], acc1[4];  // m0 acc (A->B), m1 acc (B->next A)
  float4v m1a, m1b;

  // ================= peeled i=0 =================
  STAGE_WARM(1, 1)                    // x(1) -> xp[1]
  INIT_ACC(acc0)
  ZA(acc0, m1a, 0, 0, 0)              // m0 z(0); h(-1)=0
  __syncthreads();

  INIT_ACC(acc1)
  ZA(acc1, m1b, 0, 640, 0)            // m1 z(0)
  GATES(acc0, 0, 0)                   // m0 gates(0) -> hp rows0-15
  __syncthreads();

  // ================= peeled i=1 =================
  STAGE_WARM(2, 0)                    // x(2) -> xp[0]
  INIT_ACC(acc0)
  INIT4(m1a, b1v)
  ZA(acc0, m1a, 1, 0, 1)              // m0 z(1)+MLP1(0)
  WRITE_O1(m1a, 0)                    // o1(0) rows0-15
  GATES(acc1, 4, 640)                 // m1 gates(0) -> hp rows16-31
  __syncthreads();

  INIT_ACC(acc1)
  INIT4(m1b, b1v)
  ZA(acc1, m1b, 1, 640, 1)            // m1 z(1)+MLP1(0)
  WRITE_O1(m1b, 640)                  // o1(0) rows16-31
  GATES(acc0, 0, 0)                   // m0 gates(1)
  DO_MLP2(0, 0)                       // m0 MLP2(0) -> o2s rows0-15
  __syncthreads();

  // ================= warm main: i = 2..23 (branchless regions) ============
  for (int i = 2; i < 24; ++i){
    const int xbi = i & 1, xbo = (i + 1) & 1;
    // ---- region A: m0 MFMA | m1 VALU ----
    STAGE_WARM(i + 1, xbo)            // x(i+1); step 24 -> j7 stays 0
    INIT_ACC(acc0)
    INIT4(m1a, b1v)
    ZA(acc0, m1a, xbi, 0, 1)          // m0 z(i)+MLP1(i-1)
    WRITE_O1(m1a, 0)                  // o1(i-1) rows0-15
    GATES(acc1, 4, 640)               // m1 gates(i-1) -> hp rows16-31
    DO_MLP2(640, 16)                  // m1 MLP2(i-2) -> o2s rows16-31
    HEAD_HALF(0, 0, i - 2)            // out(i-2) rows0-15 (o2 from B_{i-1})
    SGB_REGION
    __syncthreads();

    // ---- region B: m1 MFMA | m0 VALU ----
    INIT_ACC(acc1)
    INIT4(m1b, b1v)
    ZA(acc1, m1b, xbi, 640, 1)        // m1 z(i)+MLP1(i-1) (h1(i-1) from A_i)
    WRITE_O1(m1b, 640)                // o1(i-1) rows16-31
    GATES(acc0, 0, 0)                 // m0 gates(i) -> hp rows0-15
    DO_MLP2(0, 0)                     // m0 MLP2(i-1) -> o2s rows0-15
    HEAD_HALF(128, 16, i - 2)         // out(i-2) rows16-31 (o2 from A_i)
    SGB_REGION
    __syncthreads();
  }
  // After warm: h0(23) in hp (B_23), acc1 = z(23) m1; o1(22) both halves done;
  // o2(22) rows0-15 from B_23; out complete through step 21.

  // ================= drain to synchronized state =================
  GATES(acc1, 4, 640)                 // m1 gates(23) -> h1(23)
  DO_MLP2(640, 16)                    // m1 MLP2(22) -> o2s rows16-31
  HEAD_HALF(0, 0, 22)                 // out(22) rows0-15 (o2 from B_23)
  __syncthreads();
  HEAD_HALF(128, 16, 22)              // out(22) rows16-31 (o2 from drain R1)
  __syncthreads();

  // ===== tail: s = 24..29 (r7's proven TA/TB/TC/TD; p-feedback chain) =====
  for (int s = 24; s < T_STEPS; ++s){
    // ---- TA: stage x(s+1) (j7=0) | z(s)+MLP1(s-1) both m -> o1p ----
    if (s <= 28){ STAGE_TAIL(s + 1, (s + 1) & 1) }
    float4v acc[4][2];
#pragma unroll
    for (int g = 0; g < 4; ++g)
#pragma unroll
      for (int m = 0; m < 2; ++m)
#pragma unroll
        for (int r = 0; r < 4; ++r) acc[g][m][r] = bzv[g];
    float4v m1[2];
#pragma unroll
    for (int m = 0; m < 2; ++m)
#pragma unroll
      for (int r = 0; r < 4; ++r) m1[m][r] = b1v;
    {
      const _Float16* xb = xp[s & 1];
      h8 a0 = *(const h8*)&xb[aoff];
      h8 a1 = *(const h8*)&xb[640 + aoff];
#pragma unroll
      for (int g = 0; g < 4; ++g){
        acc[g][0] = MFMA16(a0, Bz[g][0], acc[g][0], 0, 0, 0);
        acc[g][1] = MFMA16(a1, Bz[g][0], acc[g][1], 0, 0, 0);
      }
    }
#pragma unroll
    for (int ks = 0; ks < 4; ++ks){
      h8 ah0 = *(const h8*)&hp[ks * 1280 + aoff];
      h8 ah1 = *(const h8*)&hp[ks * 1280 + 640 + aoff];
#pragma unroll
      for (int g = 0; g < 4; ++g){
        acc[g][0] = MFMA16(ah0, Bz[g][1 + ks], acc[g][0], 0, 0, 0);
        acc[g][1] = MFMA16(ah1, Bz[g][1 + ks], acc[g][1], 0, 0, 0);
      }
      m1[0] = MFMA16(ah0, B1f[ks], m1[0], 0, 0, 0);
      m1[1] = MFMA16(ah1, B1f[ks], m1[1], 0, 0, 0);
    }
#pragma unroll
    for (int m = 0; m < 2; ++m)
#pragma unroll
      for (int r = 0; r < 4; ++r)
        o1p[wb + m * 640 + (kq * 4 + r) * 40] = (_Float16)fmaxf(m1[m][r], 0.0f);
    __syncthreads();

    // ---- TB: MLP2(s-1) both m -> o2s ----
    DO_MLP2(0, 0)
    DO_MLP2(640, 16)
    __syncthreads();

    // ---- TC: head(s-1) full -> out, pS ----
    HEAD_HALF(0, 0, s - 1)
    HEAD_HALF(128, 16, s - 1)
    __syncthreads();

    // ---- TD: p-inject + gates(s) both m -> hp ----
#pragma unroll
    for (int m = 0; m < 2; ++m)
#pragma unroll
      for (int r = 0; r < 4; ++r){
        float pv = pS[m * 16 + kq * 4 + r];
#pragma unroll
        for (int g = 0; g < 4; ++g) acc[g][m][r] += pv * wi7[g];
      }
#pragma unroll
    for (int m = 0; m < 2; ++m)
#pragma unroll
      for (int r = 0; r < 4; ++r){
        float zi = acc[0][m][r], zf = acc[1][m][r], zg = acc[2][m][r], zo = acc[3][m][r];
        float c2 = sigm(zf) * cst[m * 4 + r] + sigm(zi) * tanh_(zg);
        cst[m * 4 + r] = c2;
        float h2 = sigm(zo) * tanh_(c2);
        hp[wb + m * 640 + (kq * 4 + r) * 40] = (_Float16)h2;
      }
    __syncthreads();
  }

  // ===== final drain: MLP1(29) | MLP2(29) | head(29) =====
  {
    float4v m1[2];
#pragma unroll
    for (int m = 0; m < 2; ++m)
#pragma unroll
      for (int r = 0; r < 4; ++r) m1[m][r] = b1v;
#pragma unroll
    for (int ks = 0; ks < 4; ++ks){
      h8 ah0 = *(const h8*)&hp[ks * 1280 + aoff];
      h8 ah1 = *(const h8*)&hp[ks * 1280 + 640 + aoff];
      m1[0] = MFMA16(ah0, B1f[ks], m1[0], 0, 0, 0);
      m1[1] = MFMA16(ah1, B1f[ks], m1[1], 0, 0, 0);
    }
#pragma unroll
    for (int m = 0; m < 2; ++m)
#pragma unroll
      for (int r = 0; r < 4; ++r)
        o1p[wb + m * 640 + (kq * 4 + r) * 40] = (_Float16)fmaxf(m1[m][r], 0.0f);
    __syncthreads();
    DO_MLP2(0, 0)
    DO_MLP2(640, 16)
    __syncthreads();
    HEAD_HALF(0, 0, 29)
    HEAD_HALF(128, 16, 29)
  }
}

extern "C" void kernel_launch(void* const* d_in, const int* in_sizes, int n_in,
                              void* d_out, int out_size, void* d_ws, size_t ws_size,
                              hipStream_t stream)
{
  (void)in_sizes; (void)n_in; (void)out_size; (void)d_ws; (void)ws_size;
  // inputs: 0..7 weather (unused), 8..14 time feats, 15 irradiance_in,
  // 16 Wi, 17 Wh, 18 b, 19 W1, 20 b1, 21 W2, 22 b2, 23 Wout, 24 bout
  FeatPtrs fp;
  for (int j = 0; j < 7; ++j) fp.f[j] = (const float*)d_in[8 + j];
  const float* irr  = (const float*)d_in[15];
  const float* Wi   = (const float*)d_in[16];
  const float* Wh   = (const float*)d_in[17];
  const float* bz   = (const float*)d_in[18];
  const float* W1   = (const float*)d_in[19];
  const float* b1   = (const float*)d_in[20];
  const float* W2   = (const float*)d_in[21];
  const float* b2   = (const float*)d_in[22];
  const float* Wout = (const float*)d_in[23];
  const float* bout = (const float*)d_in[24];

  lstm_mfma<<<dim3(256), dim3(512), 0, stream>>>(
      fp, irr, Wi, Wh, bz, W1, b1, W2, b2, Wout, bout, (float*)d_out);
}

// Round 14
// 186.373 us; speedup vs baseline: 1.0556x; 1.0556x over previous
//
#include <hip/hip_runtime.h>

// Fused LSTM(H=128) + 3-layer MLP head, fp16 MFMA (16x16x32), fp32 state.
// B=8192 rows, T=30 steps. 256 blocks x 512 threads (8 waves), 32 rows/block.
// ROUND 14 (resubmit of r13; r13 bench was a container-infra failure, no
// signal — same signature as r9 which passed on identical resubmit).
// = r11 base (86.4us) with r12 fully reverted (inline-pack spilled:
// WRITE 13MB scratch; SGB null per T19 catalog; e2e-kernel gap ~86us proved to
// be fixed harness overhead, so pack_weights kernel is free) plus two safe cuts:
//  (1) accumulator init via MFMA C-operand: acc = MFMA(ax, Bz, accI) with
//      resident bias-broadcast accI/m1I/m2I -> deletes ~24 v_mov per region.
//      BIT-IDENTICAL (MFMA computed C+A*B before; we only delete the copy).
//  (2) tail head fused into MLP2 (r10-proven shuffle+atomic form, tail-only):
//      relu(m2)*Wout, 4x shfl_xor over the 16 c16-lanes, atomicAdd into pSt.
//      Tail: 4 -> 3 barriers/step. (r10's regression was this head in WARM
//      every step; warm keeps the o2s-table head.)
// Staggered warm (r11): region A_i: m0 z(i)+MLP1(i-1) [MFMA] | m1 gates(i-1)+
// MLP2(i-2)+head(i-2) [VALU]; region B_i swaps roles. 2 barriers/step.
// Prior lessons: 2 waves/SIMD is the reg ceiling (r4/r5 spills; spill
// signature = FETCH/WRITE explosion); fp16 single precision (r7); no
// shuffle-head in warm (r10); no async gather split (r8); no SGB (r12).
// - Wave w owns output cols [16w,16w+16); 2 M-tiles (rows 0-15,16-31).
// - 16x16x32 layouts: A/B: row|col=lane&15, k=(lane>>4)*8+j; C/D: col=lane&15,
//   row=(lane>>4)*4+reg (m89-verified).
// - A-panels [16 rows][40 halfs] (32 data + 8 pad): 16B-aligned b128 reads.
// - fp32: accumulators, c-state, gates, o2, head, feedback p.

#define T_STEPS 30
#define WARM_N  24

typedef _Float16 h8 __attribute__((ext_vector_type(8)));     // 8 fp16 = 4 VGPRs
typedef __attribute__((ext_vector_type(4))) float float4v;   // MFMA 16x16 C/D

struct FeatPtrs { const float* f[7]; };

#if __has_builtin(__builtin_amdgcn_rcpf)
#define RCP(x) __builtin_amdgcn_rcpf(x)
#else
#define RCP(x) (1.0f/(x))
#endif

__device__ __forceinline__ float sigm(float x){ return RCP(1.0f + __expf(-x)); }
__device__ __forceinline__ float tanh_(float x){ return 1.0f - 2.0f*RCP(1.0f + __expf(2.0f*x)); }

// ---------------- weight pack kernel (identical to r11) ----------------
// 224 frags of 512 fp16 (1 KB each), frag elem (lane,j):
//   col16 = lane&15, kk = (lane>>4)*8 + j  (K=32 per fragment)
// frags 0..159 : z-weights [wt 0..7][g 0..3][ks 0..4]
//   ks=0: x-frag: kk<8 -> Wi[kk][col], kk>=8 -> 0
//   ks 1..4: Wh[(ks-1)*32+kk][col];  col = g*128+wt*16+col16
// frags 160..191: W1 [wt][ks 0..3]; 192..223: W2 same layout.
__global__ void pack_weights(const float* __restrict__ Wi, const float* __restrict__ Wh,
                             const float* __restrict__ W1, const float* __restrict__ W2,
                             _Float16* __restrict__ ws)
{
  int idx = blockIdx.x * 256 + threadIdx.x;
  if (idx >= 224 * 512) return;
  int f    = idx >> 9;
  int r    = idx & 511;
  int lane = r >> 3, j = r & 7;
  int kk   = ((lane >> 4) << 3) + j;     // 0..31
  int c16  = lane & 15;
  float v = 0.0f;
  if (f < 160){
    int wt = f / 20, rem = f % 20, g = rem / 5, ks = rem % 5;
    int col = g * 128 + wt * 16 + c16;
    if (ks == 0) v = (kk < 8) ? Wi[kk * 512 + col] : 0.0f;
    else         v = Wh[((ks - 1) * 32 + kk) * 512 + col];
  } else {
    int f2 = f - 160;
    const float* W = (f2 < 32) ? W1 : W2;
    int f3 = f2 & 31;
    int wt = f3 >> 2, ks = f3 & 3;
    v = W[(ks * 32 + kk) * 128 + wt * 16 + c16];
  }
  ws[idx] = (_Float16)v;
}

#define MFMA16 __builtin_amdgcn_mfma_f32_16x16x32_f16

// ---------------- region building blocks ----------------
// z-GEMM for one m-tile, acc/m1 initialized via MFMA C-operand (bit-identical
// to mov-init: MFMA computes C + A*B either way).
#define ZA(ACC, M1V, XBUF, HOFF, DO1) \
  { h8 ax_ = *(const h8*)&xp[XBUF][(HOFF) + aoff]; \
    _Pragma("unroll") for (int g_ = 0; g_ < 4; ++g_) \
      ACC[g_] = MFMA16(ax_, Bz[g_][0], accI[g_], 0, 0, 0); } \
  _Pragma("unroll") for (int ks_ = 0; ks_ < 4; ++ks_){ \
    h8 ah_ = *(const h8*)&hp[ks_ * 1280 + (HOFF) + aoff]; \
    _Pragma("unroll") for (int g_ = 0; g_ < 4; ++g_) \
      ACC[g_] = MFMA16(ah_, Bz[g_][1 + ks_], ACC[g_], 0, 0, 0); \
    if (DO1) M1V = MFMA16(ah_, B1f[ks_], (ks_ == 0) ? m1I : M1V, 0, 0, 0); }

#define WRITE_O1(M1V, HOFF) \
  _Pragma("unroll") for (int r_ = 0; r_ < 4; ++r_) \
    o1p[wb + (HOFF) + (kq * 4 + r_) * 40] = (_Float16)fmaxf(M1V[r_], 0.0f);

#define GATES(ACC, CB, HOFF) \
  _Pragma("unroll") for (int r_ = 0; r_ < 4; ++r_){ \
    float zi_ = ACC[0][r_], zf_ = ACC[1][r_], zg_ = ACC[2][r_], zo_ = ACC[3][r_]; \
    float c2_ = sigm(zf_) * cst[(CB) + r_] + sigm(zi_) * tanh_(zg_); \
    cst[(CB) + r_] = c2_; \
    float h2_ = sigm(zo_) * tanh_(c2_); \
    hp[wb + (HOFF) + (kq * 4 + r_) * 40] = (_Float16)h2_; }

#define DO_MLP2(HOFF, ROWB) \
  { h8 a0_ = *(const h8*)&o1p[(HOFF) + aoff]; \
    float4v m2_ = MFMA16(a0_, B2f[0], m2I, 0, 0, 0); \
    _Pragma("unroll") for (int ks_ = 1; ks_ < 4; ++ks_){ \
      h8 a_ = *(const h8*)&o1p[ks_ * 1280 + (HOFF) + aoff]; \
      m2_ = MFMA16(a_, B2f[ks_], m2_, 0, 0, 0); } \
    _Pragma("unroll") for (int r_ = 0; r_ < 4; ++r_) \
      o2s[((ROWB) + kq * 4 + r_) * 132 + w * 16 + c16] = fmaxf(m2_[r_], 0.0f); }

// tail-only: MLP2 + in-register head reduce -> pSt (r10-proven form)
#define MLP2_REDUCE(HOFF, MBASE) \
  { h8 a0_ = *(const h8*)&o1p[(HOFF) + aoff]; \
    float4v m2_ = MFMA16(a0_, B2f[0], m2I, 0, 0, 0); \
    _Pragma("unroll") for (int ks_ = 1; ks_ < 4; ++ks_){ \
      h8 a_ = *(const h8*)&o1p[ks_ * 1280 + (HOFF) + aoff]; \
      m2_ = MFMA16(a_, B2f[ks_], m2_, 0, 0, 0); } \
    _Pragma("unroll") for (int r_ = 0; r_ < 4; ++r_){ \
      float v_ = fmaxf(m2_[r_], 0.0f) * woutv; \
      v_ += __shfl_xor(v_, 1); v_ += __shfl_xor(v_, 2); \
      v_ += __shfl_xor(v_, 4); v_ += __shfl_xor(v_, 8); \
      if (c16 == 0) atomicAdd(&pSt[(MBASE) + kq * 4 + r_], v_); } }

// head for one 16-row half: 8 threads/row, 16-col strips, fp32 exact (warm)
#define HEAD_HALF(TLO, RB, STEP) \
  if (t >= (TLO) && t < (TLO) + 128){ \
    int r_ = (RB) + ((t - (TLO)) >> 3), jj_ = t & 7; \
    const float* orow_ = &o2s[r_ * 132 + jj_ * 16]; \
    const float* wrow_ = &WoutS[jj_ * 16]; \
    float s_ = 0.0f; \
    _Pragma("unroll") for (int q_ = 0; q_ < 16; ++q_) s_ += orow_[q_] * wrow_[q_]; \
    s_ += __shfl_down(s_, 4, 8); s_ += __shfl_down(s_, 2, 8); s_ += __shfl_down(s_, 1, 8); \
    if (jj_ == 0){ float pv_ = s_ + bout0; \
      out[(r0 + r_) * T_STEPS + (STEP)] = pv_; pS[r_] = pv_; } }

#define STAGE_WARM(STEP, BUF) \
  if (t < 256){ \
    float v_ = 0.0f; \
    if (fbase) v_ = fbase[STEP]; \
    else if ((STEP) < WARM_N) v_ = ibase[STEP]; \
    xp[BUF][xslot] = (_Float16)v_; }

#define STAGE_TAIL(STEP, BUF) \
  if (t < 256){ \
    float v_ = fbase ? fbase[STEP] : 0.0f; \
    xp[BUF][xslot] = (_Float16)v_; }

// ---------------- main kernel ----------------
__global__ __launch_bounds__(512, 2)
void lstm_mfma(FeatPtrs fp, const float* __restrict__ irr,
               const _Float16* __restrict__ wsb,
               const float* __restrict__ bz, const float* __restrict__ b1,
               const float* __restrict__ b2, const float* __restrict__ Wout,
               const float* __restrict__ bout, float* __restrict__ out)
{
  // A-panels: [m-tile][16 rows][40 halfs] (32 data + 8 pad), b128-aligned
  __shared__ __align__(16) _Float16 xp[2][1280];    // x, double-buffered steps
  __shared__ __align__(16) _Float16 hp [4 * 1280];  // h, single (halves alternate)
  __shared__ __align__(16) _Float16 o1p[4 * 1280];  // o1, single
  __shared__ __align__(16) float o2s[32 * 132];     // o2 fp32, padded rows
  __shared__ float WoutS[128];
  __shared__ float pS[32];
  __shared__ float pSt[32];                         // tail head accum

  const int t   = threadIdx.x;
  const int l   = t & 63;
  const int w   = t >> 6;        // wave 0..7, owns cols [16w,16w+16)
  const int c16 = l & 15;
  const int kq  = l >> 4;        // 0..3
  const int r0  = blockIdx.x * 32;

  // weight fragments -> registers (112 VGPRs)
  h8 Bz[4][5], B1f[4], B2f[4];
  {
    const h8* f8 = (const h8*)wsb;
#pragma unroll
    for (int g = 0; g < 4; ++g)
#pragma unroll
      for (int ks = 0; ks < 5; ++ks)
        Bz[g][ks] = f8[((w * 4 + g) * 5 + ks) * 64 + l];
#pragma unroll
    for (int ks = 0; ks < 4; ++ks) B1f[ks] = f8[(160 + w * 4 + ks) * 64 + l];
#pragma unroll
    for (int ks = 0; ks < 4; ++ks) B2f[ks] = f8[(192 + w * 4 + ks) * 64 + l];
  }
  float bzv[4], wi7[4];
#pragma unroll
  for (int g = 0; g < 4; ++g){
    bzv[g] = bz[g * 128 + w * 16 + c16];
    // Wi[7][col] as the SAME fp16 value the x-MFMA frag uses (frag elem kk=7)
    wi7[g] = (float)wsb[((w * 4 + g) * 5) * 512 + c16 * 8 + 7];
  }
  const float b1v   = b1[w * 16 + c16];
  const float b2v   = b2[w * 16 + c16];
  const float bout0 = bout[0];
  const float woutv = Wout[w * 16 + c16];   // this lane's head weight (tail)
  if (t < 128) WoutS[t] = Wout[t];

  // bias-broadcast C-operands (resident; MFMA C-init replaces mov-init)
  float4v accI[4], m1I, m2I;
#pragma unroll
  for (int g = 0; g < 4; ++g)
#pragma unroll
    for (int r = 0; r < 4; ++r) accI[g][r] = bzv[g];
#pragma unroll
  for (int r = 0; r < 4; ++r){ m1I[r] = b1v; m2I[r] = b2v; }

  // per-thread gather bases (threads t<256 own one (row,feature) slot)
  const float* fbase = nullptr;   // feature array base (j<7)
  const float* ibase = nullptr;   // irradiance base (j==7)
  int xslot = 0;
  if (t < 256){
    int r = t >> 3, j = t & 7;
    if (j < 7) fbase = fp.f[j] + (r0 + r) * T_STEPS;
    else       ibase = irr + (r0 + r) * WARM_N;
    xslot = (r >> 4) * 640 + (r & 15) * 40 + j;
  }

  { // zero x buffers (k8..31 pads stay 0 forever) and h panels (h(-1)=0)
    int* zp = (int*)&xp[0][0];
    for (int i = t; i < 1280; i += 512) zp[i] = 0;
    zp = (int*)hp;
    for (int i = t; i < 2560; i += 512) zp[i] = 0;
  }

  float cst[8];   // [0..3]=m0 rows0-15, [4..7]=m1 rows16-31
#pragma unroll
  for (int i = 0; i < 8; ++i) cst[i] = 0.0f;

  const int aoff = c16 * 40 + kq * 8;                    // A-frag read offset
  const int wb   = (w >> 1) * 1280 + (w & 1) * 16 + c16; // h/o1 write base
  __syncthreads();

  // prologue: gather x(0) into xp[0]
  if (t < 256){
    float v0 = fbase ? fbase[0] : ibase[0];
    xp[0][xslot] = (_Float16)v0;
  }
  __syncthreads();

  float4v acc0[4], acc1[4];  // m0 acc (A->B), m1 acc (B->next A)
  float4v m1a, m1b;

  // ================= peeled i=0 =================
  STAGE_WARM(1, 1)                    // x(1) -> xp[1]
  ZA(acc0, m1a, 0, 0, 0)              // m0 z(0); h(-1)=0
  __syncthreads();

  ZA(acc1, m1b, 0, 640, 0)            // m1 z(0)
  GATES(acc0, 0, 0)                   // m0 gates(0) -> hp rows0-15
  __syncthreads();

  // ================= peeled i=1 =================
  STAGE_WARM(2, 0)                    // x(2) -> xp[0]
  ZA(acc0, m1a, 1, 0, 1)              // m0 z(1)+MLP1(0)
  WRITE_O1(m1a, 0)                    // o1(0) rows0-15
  GATES(acc1, 4, 640)                 // m1 gates(0) -> hp rows16-31
  __syncthreads();

  ZA(acc1, m1b, 1, 640, 1)            // m1 z(1)+MLP1(0)
  WRITE_O1(m1b, 640)                  // o1(0) rows16-31
  GATES(acc0, 0, 0)                   // m0 gates(1)
  DO_MLP2(0, 0)                       // m0 MLP2(0) -> o2s rows0-15
  __syncthreads();

  // ================= warm main: i = 2..23 (branchless regions) ============
  for (int i = 2; i < 24; ++i){
    const int xbi = i & 1, xbo = (i + 1) & 1;
    // ---- region A: m0 MFMA | m1 VALU ----
    STAGE_WARM(i + 1, xbo)            // x(i+1); step 24 -> j7 stays 0
    ZA(acc0, m1a, xbi, 0, 1)          // m0 z(i)+MLP1(i-1)
    WRITE_O1(m1a, 0)                  // o1(i-1) rows0-15
    GATES(acc1, 4, 640)               // m1 gates(i-1) -> hp rows16-31
    DO_MLP2(640, 16)                  // m1 MLP2(i-2) -> o2s rows16-31
    HEAD_HALF(0, 0, i - 2)            // out(i-2) rows0-15 (o2 from B_{i-1})
    __syncthreads();

    // ---- region B: m1 MFMA | m0 VALU ----
    ZA(acc1, m1b, xbi, 640, 1)        // m1 z(i)+MLP1(i-1) (h1(i-1) from A_i)
    WRITE_O1(m1b, 640)                // o1(i-1) rows16-31
    GATES(acc0, 0, 0)                 // m0 gates(i) -> hp rows0-15
    DO_MLP2(0, 0)                     // m0 MLP2(i-1) -> o2s rows0-15
    HEAD_HALF(128, 16, i - 2)         // out(i-2) rows16-31 (o2 from A_i)
    __syncthreads();
  }
  // After warm: h0(23) in hp (B_23), acc1 = z(23) m1; o1(22) both halves done;
  // o2(22) rows0-15 from B_23; out complete through step 21.

  // ================= drain to synchronized state =================
  GATES(acc1, 4, 640)                 // m1 gates(23) -> h1(23)
  DO_MLP2(640, 16)                    // m1 MLP2(22) -> o2s rows16-31
  HEAD_HALF(0, 0, 22)                 // out(22) rows0-15 (o2 from B_23)
  __syncthreads();
  HEAD_HALF(128, 16, 22)              // out(22) rows16-31 (o2 from drain R1)
  __syncthreads();

  // ===== tail: s = 24..29, 3 barriers/step (head fused into MLP2) =====
  for (int s = 24; s < T_STEPS; ++s){
    // ---- TA: stage x(s+1) (j7=0) | pSt=bout0 | z(s)+MLP1(s-1) -> o1p ----
    if (s <= 28){ STAGE_TAIL(s + 1, (s + 1) & 1) }
    if (t < 32) pSt[t] = bout0;
    float4v acc[4][2];
    float4v m1[2];
    {
      const _Float16* xb = xp[s & 1];
      h8 a0 = *(const h8*)&xb[aoff];
      h8 a1 = *(const h8*)&xb[640 + aoff];
#pragma unroll
      for (int g = 0; g < 4; ++g){
        acc[g][0] = MFMA16(a0, Bz[g][0], accI[g], 0, 0, 0);
        acc[g][1] = MFMA16(a1, Bz[g][0], accI[g], 0, 0, 0);
      }
    }
#pragma unroll
    for (int ks = 0; ks < 4; ++ks){
      h8 ah0 = *(const h8*)&hp[ks * 1280 + aoff];
      h8 ah1 = *(const h8*)&hp[ks * 1280 + 640 + aoff];
#pragma unroll
      for (int g = 0; g < 4; ++g){
        acc[g][0] = MFMA16(ah0, Bz[g][1 + ks], acc[g][0], 0, 0, 0);
        acc[g][1] = MFMA16(ah1, Bz[g][1 + ks], acc[g][1], 0, 0, 0);
      }
      m1[0] = MFMA16(ah0, B1f[ks], (ks == 0) ? m1I : m1[0], 0, 0, 0);
      m1[1] = MFMA16(ah1, B1f[ks], (ks == 0) ? m1I : m1[1], 0, 0, 0);
    }
#pragma unroll
    for (int m = 0; m < 2; ++m)
#pragma unroll
      for (int r = 0; r < 4; ++r)
        o1p[wb + m * 640 + (kq * 4 + r) * 40] = (_Float16)fmaxf(m1[m][r], 0.0f);
    __syncthreads();

    // ---- TB: MLP2(s-1) + in-reg head reduce -> pSt (= p(s-1)) ----
    MLP2_REDUCE(0, 0)
    MLP2_REDUCE(640, 16)
    __syncthreads();

    // ---- TD: out(s-1) | p-inject + gates(s) -> hp ----
    if (t < 32) out[(r0 + t) * T_STEPS + (s - 1)] = pSt[t];
#pragma unroll
    for (int m = 0; m < 2; ++m)
#pragma unroll
      for (int r = 0; r < 4; ++r){
        float pv = pSt[m * 16 + kq * 4 + r];
#pragma unroll
        for (int g = 0; g < 4; ++g) acc[g][m][r] += pv * wi7[g];
      }
#pragma unroll
    for (int m = 0; m < 2; ++m)
#pragma unroll
      for (int r = 0; r < 4; ++r){
        float zi = acc[0][m][r], zf = acc[1][m][r], zg = acc[2][m][r], zo = acc[3][m][r];
        float c2 = sigm(zf) * cst[m * 4 + r] + sigm(zi) * tanh_(zg);
        cst[m * 4 + r] = c2;
        float h2 = sigm(zo) * tanh_(c2);
        hp[wb + m * 640 + (kq * 4 + r) * 40] = (_Float16)h2;
      }
    __syncthreads();
  }

  // ===== final drain: MLP1(29) | MLP2(29)+reduce | out(29) =====
  {
    if (t < 32) pSt[t] = bout0;
    float4v m1[2];
#pragma unroll
    for (int ks = 0; ks < 4; ++ks){
      h8 ah0 = *(const h8*)&hp[ks * 1280 + aoff];
      h8 ah1 = *(const h8*)&hp[ks * 1280 + 640 + aoff];
      m1[0] = MFMA16(ah0, B1f[ks], (ks == 0) ? m1I : m1[0], 0, 0, 0);
      m1[1] = MFMA16(ah1, B1f[ks], (ks == 0) ? m1I : m1[1], 0, 0, 0);
    }
#pragma unroll
    for (int m = 0; m < 2; ++m)
#pragma unroll
      for (int r = 0; r < 4; ++r)
        o1p[wb + m * 640 + (kq * 4 + r) * 40] = (_Float16)fmaxf(m1[m][r], 0.0f);
    __syncthreads();

    MLP2_REDUCE(0, 0)
    MLP2_REDUCE(640, 16)
    __syncthreads();

    if (t < 32) out[(r0 + t) * T_STEPS + 29] = pSt[t];
  }
}

extern "C" void kernel_launch(void* const* d_in, const int* in_sizes, int n_in,
                              void* d_out, int out_size, void* d_ws, size_t ws_size,
                              hipStream_t stream)
{
  (void)in_sizes; (void)n_in; (void)out_size; (void)ws_size;
  // inputs: 0..7 weather (unused), 8..14 time feats, 15 irradiance_in,
  // 16 Wi, 17 Wh, 18 b, 19 W1, 20 b1, 21 W2, 22 b2, 23 Wout, 24 bout
  FeatPtrs fp;
  for (int j = 0; j < 7; ++j) fp.f[j] = (const float*)d_in[8 + j];
  const float* irr  = (const float*)d_in[15];
  const float* Wi   = (const float*)d_in[16];
  const float* Wh   = (const float*)d_in[17];
  const float* bz   = (const float*)d_in[18];
  const float* W1   = (const float*)d_in[19];
  const float* b1   = (const float*)d_in[20];
  const float* W2   = (const float*)d_in[21];
  const float* b2   = (const float*)d_in[22];
  const float* Wout = (const float*)d_in[23];
  const float* bout = (const float*)d_in[24];

  _Float16* ws = (_Float16*)d_ws;                 // 224*512*2 = 224 KB used
  pack_weights<<<dim3(448), dim3(256), 0, stream>>>(Wi, Wh, W1, W2, ws);
  lstm_mfma<<<dim3(256), dim3(512), 0, stream>>>(
      fp, irr, ws, bz, b1, b2, Wout, bout, (float*)d_out);
}

// Round 15
// 178.349 us; speedup vs baseline: 1.1031x; 1.0450x over previous
//
#include <hip/hip_runtime.h>

// Fused LSTM(H=128) + 3-layer MLP head, fp16 MFMA (16x16x32), fp32 state.
// B=8192 rows, T=30 steps. 256 blocks x 512 threads (8 waves), 32 rows/block.
// ROUND 15 = EXACT r11 (session best: 86.4us kernel / 177.9us e2e), locking in
// the best verified state. r13/r14's bundled micro-opts regressed to 92.2us:
// MFMA C-operand init forces accvgpr copies (C live-across => dst can't alias),
// costlier than the v_movs it deleted. All reverted.
// Verdict on the plateau: MfmaUtil 26 + VALUBusy 50 = 76% combined, HBM 0.8%,
// no pipe saturated -> latency-bound structure, not a pipe roofline. Measured
// levers: mega-region r10 -40%; SGB r12 null; async-gather r8 -3%; micro-init
// r14 -6%; >2 waves/SIMD r4/r5 spill. Remaining idea (wave-group role swap)
// needs double-versioned h panels + step skew; EV judged negative.
// STRUCTURE (r11): staggered M-tiles. Region A_i: m0 z(i)+MLP1(i-1) [MFMA] |
// m1 gates(i-1)+MLP2(i-2)+head(i-2) [VALU]; region B_i swaps roles.
// 2 barriers/warm step. Tail s=24..29: r7's TA/TB/TC/TD (p-inject acc+=p*wi7).
// Prior lessons: 2 waves/SIMD is the reg ceiling (r4/r5 spills); fp16 single
// precision (r7, absmax 0.001953125); no shuffle-head in warm (r10); no async
// gather split (r8); no SGB (r12); no MFMA C-init (r14).
// - Wave w owns output cols [16w,16w+16); 2 M-tiles (rows 0-15,16-31).
// - 16x16x32 layouts: A/B: row|col=lane&15, k=(lane>>4)*8+j; C/D: col=lane&15,
//   row=(lane>>4)*4+reg (m89-verified).
// - A-panels [16 rows][40 halfs] (32 data + 8 pad): 16B-aligned b128 reads.
// - fp32: accumulators, c-state, gates, o2, head, feedback p.

#define T_STEPS 30
#define WARM_N  24

typedef _Float16 h8 __attribute__((ext_vector_type(8)));     // 8 fp16 = 4 VGPRs
typedef __attribute__((ext_vector_type(4))) float float4v;   // MFMA 16x16 C/D

struct FeatPtrs { const float* f[7]; };

#if __has_builtin(__builtin_amdgcn_rcpf)
#define RCP(x) __builtin_amdgcn_rcpf(x)
#else
#define RCP(x) (1.0f/(x))
#endif

__device__ __forceinline__ float sigm(float x){ return RCP(1.0f + __expf(-x)); }
__device__ __forceinline__ float tanh_(float x){ return 1.0f - 2.0f*RCP(1.0f + __expf(2.0f*x)); }

// ---------------- weight pack kernel ----------------
// 224 frags of 512 fp16 (1 KB each), frag elem (lane,j):
//   col16 = lane&15, kk = (lane>>4)*8 + j  (K=32 per fragment)
// frags 0..159 : z-weights [wt 0..7][g 0..3][ks 0..4]
//   ks=0: x-frag: kk<8 -> Wi[kk][col], kk>=8 -> 0
//   ks 1..4: Wh[(ks-1)*32+kk][col];  col = g*128+wt*16+col16
// frags 160..191: W1 [wt][ks 0..3]; 192..223: W2 same layout.
__global__ void pack_weights(const float* __restrict__ Wi, const float* __restrict__ Wh,
                             const float* __restrict__ W1, const float* __restrict__ W2,
                             _Float16* __restrict__ ws)
{
  int idx = blockIdx.x * 256 + threadIdx.x;
  if (idx >= 224 * 512) return;
  int f    = idx >> 9;
  int r    = idx & 511;
  int lane = r >> 3, j = r & 7;
  int kk   = ((lane >> 4) << 3) + j;     // 0..31
  int c16  = lane & 15;
  float v = 0.0f;
  if (f < 160){
    int wt = f / 20, rem = f % 20, g = rem / 5, ks = rem % 5;
    int col = g * 128 + wt * 16 + c16;
    if (ks == 0) v = (kk < 8) ? Wi[kk * 512 + col] : 0.0f;
    else         v = Wh[((ks - 1) * 32 + kk) * 512 + col];
  } else {
    int f2 = f - 160;
    const float* W = (f2 < 32) ? W1 : W2;
    int f3 = f2 & 31;
    int wt = f3 >> 2, ks = f3 & 3;
    v = W[(ks * 32 + kk) * 128 + wt * 16 + c16];
  }
  ws[idx] = (_Float16)v;
}

#define MFMA16 __builtin_amdgcn_mfma_f32_16x16x32_f16

// ---------------- region building blocks ----------------
#define INIT_ACC(ACC) \
  _Pragma("unroll") for (int g_ = 0; g_ < 4; ++g_) \
    _Pragma("unroll") for (int r_ = 0; r_ < 4; ++r_) ACC[g_][r_] = bzv[g_];

#define INIT4(V, B) \
  _Pragma("unroll") for (int r_ = 0; r_ < 4; ++r_) V[r_] = (B);

// z-GEMM for one m-tile (+ optionally MLP1 fused on the same h reads)
#define ZA(ACC, M1V, XBUF, HOFF, DO1) \
  { h8 ax_ = *(const h8*)&xp[XBUF][(HOFF) + aoff]; \
    _Pragma("unroll") for (int g_ = 0; g_ < 4; ++g_) \
      ACC[g_] = MFMA16(ax_, Bz[g_][0], ACC[g_], 0, 0, 0); } \
  _Pragma("unroll") for (int ks_ = 0; ks_ < 4; ++ks_){ \
    h8 ah_ = *(const h8*)&hp[ks_ * 1280 + (HOFF) + aoff]; \
    _Pragma("unroll") for (int g_ = 0; g_ < 4; ++g_) \
      ACC[g_] = MFMA16(ah_, Bz[g_][1 + ks_], ACC[g_], 0, 0, 0); \
    if (DO1) M1V = MFMA16(ah_, B1f[ks_], M1V, 0, 0, 0); }

#define WRITE_O1(M1V, HOFF) \
  _Pragma("unroll") for (int r_ = 0; r_ < 4; ++r_) \
    o1p[wb + (HOFF) + (kq * 4 + r_) * 40] = (_Float16)fmaxf(M1V[r_], 0.0f);

#define GATES(ACC, CB, HOFF) \
  _Pragma("unroll") for (int r_ = 0; r_ < 4; ++r_){ \
    float zi_ = ACC[0][r_], zf_ = ACC[1][r_], zg_ = ACC[2][r_], zo_ = ACC[3][r_]; \
    float c2_ = sigm(zf_) * cst[(CB) + r_] + sigm(zi_) * tanh_(zg_); \
    cst[(CB) + r_] = c2_; \
    float h2_ = sigm(zo_) * tanh_(c2_); \
    hp[wb + (HOFF) + (kq * 4 + r_) * 40] = (_Float16)h2_; }

#define DO_MLP2(HOFF, ROWB) \
  { float4v m2_; INIT4(m2_, b2v) \
    _Pragma("unroll") for (int ks_ = 0; ks_ < 4; ++ks_){ \
      h8 a_ = *(const h8*)&o1p[ks_ * 1280 + (HOFF) + aoff]; \
      m2_ = MFMA16(a_, B2f[ks_], m2_, 0, 0, 0); } \
    _Pragma("unroll") for (int r_ = 0; r_ < 4; ++r_) \
      o2s[((ROWB) + kq * 4 + r_) * 132 + w * 16 + c16] = fmaxf(m2_[r_], 0.0f); }

// head for one 16-row half: 8 threads/row, 16-col strips, fp32 exact
#define HEAD_HALF(TLO, RB, STEP) \
  if (t >= (TLO) && t < (TLO) + 128){ \
    int r_ = (RB) + ((t - (TLO)) >> 3), jj_ = t & 7; \
    const float* orow_ = &o2s[r_ * 132 + jj_ * 16]; \
    const float* wrow_ = &WoutS[jj_ * 16]; \
    float s_ = 0.0f; \
    _Pragma("unroll") for (int q_ = 0; q_ < 16; ++q_) s_ += orow_[q_] * wrow_[q_]; \
    s_ += __shfl_down(s_, 4, 8); s_ += __shfl_down(s_, 2, 8); s_ += __shfl_down(s_, 1, 8); \
    if (jj_ == 0){ float pv_ = s_ + bout0; \
      out[(r0 + r_) * T_STEPS + (STEP)] = pv_; pS[r_] = pv_; } }

#define STAGE_WARM(STEP, BUF) \
  if (t < 256){ \
    float v_ = 0.0f; \
    if (fbase) v_ = fbase[STEP]; \
    else if ((STEP) < WARM_N) v_ = ibase[STEP]; \
    xp[BUF][xslot] = (_Float16)v_; }

#define STAGE_TAIL(STEP, BUF) \
  if (t < 256){ \
    float v_ = fbase ? fbase[STEP] : 0.0f; \
    xp[BUF][xslot] = (_Float16)v_; }

// ---------------- main kernel ----------------
__global__ __launch_bounds__(512, 2)
void lstm_mfma(FeatPtrs fp, const float* __restrict__ irr,
               const _Float16* __restrict__ wsb,
               const float* __restrict__ bz, const float* __restrict__ b1,
               const float* __restrict__ b2, const float* __restrict__ Wout,
               const float* __restrict__ bout, float* __restrict__ out)
{
  // A-panels: [m-tile][16 rows][40 halfs] (32 data + 8 pad), b128-aligned
  __shared__ __align__(16) _Float16 xp[2][1280];    // x, double-buffered steps
  __shared__ __align__(16) _Float16 hp [4 * 1280];  // h, single (halves alternate)
  __shared__ __align__(16) _Float16 o1p[4 * 1280];  // o1, single
  __shared__ __align__(16) float o2s[32 * 132];     // o2 fp32, padded rows
  __shared__ float WoutS[128];
  __shared__ float pS[32];

  const int t   = threadIdx.x;
  const int l   = t & 63;
  const int w   = t >> 6;        // wave 0..7, owns cols [16w,16w+16)
  const int c16 = l & 15;
  const int kq  = l >> 4;        // 0..3
  const int r0  = blockIdx.x * 32;

  // weight fragments -> registers (112 VGPRs)
  h8 Bz[4][5], B1f[4], B2f[4];
  {
    const h8* f8 = (const h8*)wsb;
#pragma unroll
    for (int g = 0; g < 4; ++g)
#pragma unroll
      for (int ks = 0; ks < 5; ++ks)
        Bz[g][ks] = f8[((w * 4 + g) * 5 + ks) * 64 + l];
#pragma unroll
    for (int ks = 0; ks < 4; ++ks) B1f[ks] = f8[(160 + w * 4 + ks) * 64 + l];
#pragma unroll
    for (int ks = 0; ks < 4; ++ks) B2f[ks] = f8[(192 + w * 4 + ks) * 64 + l];
  }
  float bzv[4], wi7[4];
#pragma unroll
  for (int g = 0; g < 4; ++g){
    bzv[g] = bz[g * 128 + w * 16 + c16];
    // Wi[7][col] as the SAME fp16 value the x-MFMA frag uses (frag elem kk=7)
    wi7[g] = (float)wsb[((w * 4 + g) * 5) * 512 + c16 * 8 + 7];
  }
  const float b1v   = b1[w * 16 + c16];
  const float b2v   = b2[w * 16 + c16];
  const float bout0 = bout[0];
  if (t < 128) WoutS[t] = Wout[t];

  // per-thread gather bases (threads t<256 own one (row,feature) slot)
  const float* fbase = nullptr;   // feature array base (j<7)
  const float* ibase = nullptr;   // irradiance base (j==7)
  int xslot = 0;
  if (t < 256){
    int r = t >> 3, j = t & 7;
    if (j < 7) fbase = fp.f[j] + (r0 + r) * T_STEPS;
    else       ibase = irr + (r0 + r) * WARM_N;
    xslot = (r >> 4) * 640 + (r & 15) * 40 + j;
  }

  { // zero x buffers (k8..31 pads stay 0 forever) and h panels (h(-1)=0)
    int* zp = (int*)&xp[0][0];
    for (int i = t; i < 1280; i += 512) zp[i] = 0;
    zp = (int*)hp;
    for (int i = t; i < 2560; i += 512) zp[i] = 0;
  }

  float cst[8];   // [0..3]=m0 rows0-15, [4..7]=m1 rows16-31
#pragma unroll
  for (int i = 0; i < 8; ++i) cst[i] = 0.0f;

  const int aoff = c16 * 40 + kq * 8;                    // A-frag read offset
  const int wb   = (w >> 1) * 1280 + (w & 1) * 16 + c16; // h/o1 write base
  __syncthreads();

  // prologue: gather x(0) into xp[0]
  if (t < 256){
    float v0 = fbase ? fbase[0] : ibase[0];
    xp[0][xslot] = (_Float16)v0;
  }
  __syncthreads();

  float4v acc0[4], acc1[4];  // m0 acc (A->B), m1 acc (B->next A)
  float4v m1a, m1b;

  // ================= peeled i=0 =================
  STAGE_WARM(1, 1)                    // x(1) -> xp[1]
  INIT_ACC(acc0)
  ZA(acc0, m1a, 0, 0, 0)              // m0 z(0); h(-1)=0
  __syncthreads();

  INIT_ACC(acc1)
  ZA(acc1, m1b, 0, 640, 0)            // m1 z(0)
  GATES(acc0, 0, 0)                   // m0 gates(0) -> hp rows0-15
  __syncthreads();

  // ================= peeled i=1 =================
  STAGE_WARM(2, 0)                    // x(2) -> xp[0]
  INIT_ACC(acc0)
  INIT4(m1a, b1v)
  ZA(acc0, m1a, 1, 0, 1)              // m0 z(1)+MLP1(0)
  WRITE_O1(m1a, 0)                    // o1(0) rows0-15
  GATES(acc1, 4, 640)                 // m1 gates(0) -> hp rows16-31
  __syncthreads();

  INIT_ACC(acc1)
  INIT4(m1b, b1v)
  ZA(acc1, m1b, 1, 640, 1)            // m1 z(1)+MLP1(0)
  WRITE_O1(m1b, 640)                  // o1(0) rows16-31
  GATES(acc0, 0, 0)                   // m0 gates(1)
  DO_MLP2(0, 0)                       // m0 MLP2(0) -> o2s rows0-15
  __syncthreads();

  // ================= warm main: i = 2..23 (branchless regions) ============
  for (int i = 2; i < 24; ++i){
    const int xbi = i & 1, xbo = (i + 1) & 1;
    // ---- region A: m0 MFMA | m1 VALU ----
    STAGE_WARM(i + 1, xbo)            // x(i+1); step 24 -> j7 stays 0
    INIT_ACC(acc0)
    INIT4(m1a, b1v)
    ZA(acc0, m1a, xbi, 0, 1)          // m0 z(i)+MLP1(i-1)
    WRITE_O1(m1a, 0)                  // o1(i-1) rows0-15
    GATES(acc1, 4, 640)               // m1 gates(i-1) -> hp rows16-31
    DO_MLP2(640, 16)                  // m1 MLP2(i-2) -> o2s rows16-31
    HEAD_HALF(0, 0, i - 2)            // out(i-2) rows0-15 (o2 from B_{i-1})
    __syncthreads();

    // ---- region B: m1 MFMA | m0 VALU ----
    INIT_ACC(acc1)
    INIT4(m1b, b1v)
    ZA(acc1, m1b, xbi, 640, 1)        // m1 z(i)+MLP1(i-1) (h1(i-1) from A_i)
    WRITE_O1(m1b, 640)                // o1(i-1) rows16-31
    GATES(acc0, 0, 0)                 // m0 gates(i) -> hp rows0-15
    DO_MLP2(0, 0)                     // m0 MLP2(i-1) -> o2s rows0-15
    HEAD_HALF(128, 16, i - 2)         // out(i-2) rows16-31 (o2 from A_i)
    __syncthreads();
  }
  // After warm: h0(23) in hp (B_23), acc1 = z(23) m1; o1(22) both halves done;
  // o2(22) rows0-15 from B_23; out complete through step 21.

  // ================= drain to synchronized state =================
  GATES(acc1, 4, 640)                 // m1 gates(23) -> h1(23)
  DO_MLP2(640, 16)                    // m1 MLP2(22) -> o2s rows16-31
  HEAD_HALF(0, 0, 22)                 // out(22) rows0-15 (o2 from B_23)
  __syncthreads();
  HEAD_HALF(128, 16, 22)              // out(22) rows16-31 (o2 from drain R1)
  __syncthreads();

  // ===== tail: s = 24..29 (r7's proven TA/TB/TC/TD; p-feedback chain) =====
  for (int s = 24; s < T_STEPS; ++s){
    // ---- TA: stage x(s+1) (j7=0) | z(s)+MLP1(s-1) both m -> o1p ----
    if (s <= 28){ STAGE_TAIL(s + 1, (s + 1) & 1) }
    float4v acc[4][2];
#pragma unroll
    for (int g = 0; g < 4; ++g)
#pragma unroll
      for (int m = 0; m < 2; ++m)
#pragma unroll
        for (int r = 0; r < 4; ++r) acc[g][m][r] = bzv[g];
    float4v m1[2];
#pragma unroll
    for (int m = 0; m < 2; ++m)
#pragma unroll
      for (int r = 0; r < 4; ++r) m1[m][r] = b1v;
    {
      const _Float16* xb = xp[s & 1];
      h8 a0 = *(const h8*)&xb[aoff];
      h8 a1 = *(const h8*)&xb[640 + aoff];
#pragma unroll
      for (int g = 0; g < 4; ++g){
        acc[g][0] = MFMA16(a0, Bz[g][0], acc[g][0], 0, 0, 0);
        acc[g][1] = MFMA16(a1, Bz[g][0], acc[g][1], 0, 0, 0);
      }
    }
#pragma unroll
    for (int ks = 0; ks < 4; ++ks){
      h8 ah0 = *(const h8*)&hp[ks * 1280 + aoff];
      h8 ah1 = *(const h8*)&hp[ks * 1280 + 640 + aoff];
#pragma unroll
      for (int g = 0; g < 4; ++g){
        acc[g][0] = MFMA16(ah0, Bz[g][1 + ks], acc[g][0], 0, 0, 0);
        acc[g][1] = MFMA16(ah1, Bz[g][1 + ks], acc[g][1], 0, 0, 0);
      }
      m1[0] = MFMA16(ah0, B1f[ks], m1[0], 0, 0, 0);
      m1[1] = MFMA16(ah1, B1f[ks], m1[1], 0, 0, 0);
    }
#pragma unroll
    for (int m = 0; m < 2; ++m)
#pragma unroll
      for (int r = 0; r < 4; ++r)
        o1p[wb + m * 640 + (kq * 4 + r) * 40] = (_Float16)fmaxf(m1[m][r], 0.0f);
    __syncthreads();

    // ---- TB: MLP2(s-1) both m -> o2s ----
    DO_MLP2(0, 0)
    DO_MLP2(640, 16)
    __syncthreads();

    // ---- TC: head(s-1) full -> out, pS ----
    HEAD_HALF(0, 0, s - 1)
    HEAD_HALF(128, 16, s - 1)
    __syncthreads();

    // ---- TD: p-inject + gates(s) both m -> hp ----
#pragma unroll
    for (int m = 0; m < 2; ++m)
#pragma unroll
      for (int r = 0; r < 4; ++r){
        float pv = pS[m * 16 + kq * 4 + r];
#pragma unroll
        for (int g = 0; g < 4; ++g) acc[g][m][r] += pv * wi7[g];
      }
#pragma unroll
    for (int m = 0; m < 2; ++m)
#pragma unroll
      for (int r = 0; r < 4; ++r){
        float zi = acc[0][m][r], zf = acc[1][m][r], zg = acc[2][m][r], zo = acc[3][m][r];
        float c2 = sigm(zf) * cst[m * 4 + r] + sigm(zi) * tanh_(zg);
        cst[m * 4 + r] = c2;
        float h2 = sigm(zo) * tanh_(c2);
        hp[wb + m * 640 + (kq * 4 + r) * 40] = (_Float16)h2;
      }
    __syncthreads();
  }

  // ===== final drain: MLP1(29) | MLP2(29) | head(29) =====
  {
    float4v m1[2];
#pragma unroll
    for (int m = 0; m < 2; ++m)
#pragma unroll
      for (int r = 0; r < 4; ++r) m1[m][r] = b1v;
#pragma unroll
    for (int ks = 0; ks < 4; ++ks){
      h8 ah0 = *(const h8*)&hp[ks * 1280 + aoff];
      h8 ah1 = *(const h8*)&hp[ks * 1280 + 640 + aoff];
      m1[0] = MFMA16(ah0, B1f[ks], m1[0], 0, 0, 0);
      m1[1] = MFMA16(ah1, B1f[ks], m1[1], 0, 0, 0);
    }
#pragma unroll
    for (int m = 0; m < 2; ++m)
#pragma unroll
      for (int r = 0; r < 4; ++r)
        o1p[wb + m * 640 + (kq * 4 + r) * 40] = (_Float16)fmaxf(m1[m][r], 0.0f);
    __syncthreads();
    DO_MLP2(0, 0)
    DO_MLP2(640, 16)
    __syncthreads();
    HEAD_HALF(0, 0, 29)
    HEAD_HALF(128, 16, 29)
  }
}

extern "C" void kernel_launch(void* const* d_in, const int* in_sizes, int n_in,
                              void* d_out, int out_size, void* d_ws, size_t ws_size,
                              hipStream_t stream)
{
  (void)in_sizes; (void)n_in; (void)out_size; (void)ws_size;
  // inputs: 0..7 weather (unused), 8..14 time feats, 15 irradiance_in,
  // 16 Wi, 17 Wh, 18 b, 19 W1, 20 b1, 21 W2, 22 b2, 23 Wout, 24 bout
  FeatPtrs fp;
  for (int j = 0; j < 7; ++j) fp.f[j] = (const float*)d_in[8 + j];
  const float* irr  = (const float*)d_in[15];
  const float* Wi   = (const float*)d_in[16];
  const float* Wh   = (const float*)d_in[17];
  const float* bz   = (const float*)d_in[18];
  const float* W1   = (const float*)d_in[19];
  const float* b1   = (const float*)d_in[20];
  const float* W2   = (const float*)d_in[21];
  const float* b2   = (const float*)d_in[22];
  const float* Wout = (const float*)d_in[23];
  const float* bout = (const float*)d_in[24];

  _Float16* ws = (_Float16*)d_ws;                 // 224*512*2 = 224 KB used
  pack_weights<<<dim3(448), dim3(256), 0, stream>>>(Wi, Wh, W1, W2, ws);
  lstm_mfma<<<dim3(256), dim3(512), 0, stream>>>(
      fp, irr, ws, bz, b1, b2, Wout, bout, (float*)d_out);
}